// Round 3
// baseline (505.736 us; speedup 1.0000x reference)
//
#include <hip/hip_runtime.h>
#include <math.h>

#define NL 6
#define DD 128
#define HH 16

typedef float v2f __attribute__((ext_vector_type(2)));

// packed-layer layout in d_ws (v2f units): per layer l:
//   [0,2048) W1 | [2048,2304) W2 | [2304,2560) W3 | [2560,2816) W4 | [2816,4864) W5
//   [4864) b1 [4880) b2 [4896) b3 [4912) b4 [4928,5056) b5
#define L_F2 5056

static __device__ __forceinline__ v2f pk_fma(v2f a, v2f b, v2f c){
#if __has_builtin(__builtin_elementwise_fma)
    return __builtin_elementwise_fma(a, b, c);
#else
    v2f r; r.x = fmaf(a.x,b.x,c.x); r.y = fmaf(a.y,b.y,c.y); return r;
#endif
}
static __device__ __forceinline__ v2f pk_relu(v2f a){
#if __has_builtin(__builtin_elementwise_max)
    return __builtin_elementwise_max(a, (v2f)0.f);
#else
    v2f r; r.x = fmaxf(a.x,0.f); r.y = fmaxf(a.y,0.f); return r;
#endif
}
static __device__ __forceinline__ v2f flo(float4 w){ v2f r; r.x=w.x; r.y=w.y; return r; }
static __device__ __forceinline__ v2f fhi(float4 w){ v2f r; r.x=w.z; r.y=w.w; return r; }

__global__ void pack_weights(
    const float* __restrict__ tW1, const float* __restrict__ sW1,
    const float* __restrict__ tW2, const float* __restrict__ sW2,
    const float* __restrict__ tW3, const float* __restrict__ sW3,
    const float* __restrict__ tW4, const float* __restrict__ sW4,
    const float* __restrict__ tW5, const float* __restrict__ sW5,
    const float* __restrict__ tb1, const float* __restrict__ sb1,
    const float* __restrict__ tb2, const float* __restrict__ sb2,
    const float* __restrict__ tb3, const float* __restrict__ sb3,
    const float* __restrict__ tb4, const float* __restrict__ sb4,
    const float* __restrict__ tb5, const float* __restrict__ sb5,
    v2f* __restrict__ pw)
{
    const int l = blockIdx.x, t = threadIdx.x;
    v2f* base = pw + (size_t)l * L_F2;
    for (int i = t; i < 2048; i += 256) base[i]      = (v2f){tW1[l*2048+i], sW1[l*2048+i]};
    for (int i = t; i < 256;  i += 256) base[2048+i] = (v2f){tW2[l*256 +i], sW2[l*256 +i]};
    for (int i = t; i < 256;  i += 256) base[2304+i] = (v2f){tW3[l*256 +i], sW3[l*256 +i]};
    for (int i = t; i < 256;  i += 256) base[2560+i] = (v2f){tW4[l*256 +i], sW4[l*256 +i]};
    for (int i = t; i < 2048; i += 256) base[2816+i] = (v2f){tW5[l*2048+i], sW5[l*2048+i]};
    if (t < 16){
        base[4864+t] = (v2f){tb1[l*16+t], sb1[l*16+t]};
        base[4880+t] = (v2f){tb2[l*16+t], sb2[l*16+t]};
        base[4896+t] = (v2f){tb3[l*16+t], sb3[l*16+t]};
        base[4912+t] = (v2f){tb4[l*16+t], sb4[l*16+t]};
    }
    for (int i = t; i < 128; i += 256) base[4928+i] = (v2f){tb5[l*128+i], sb5[l*128+i]};
}

// 2 rows/thread; weights streamed via VMEM (vz pins addressing to a VGPR so the
// compiler emits global_load_dwordx4 with vmcnt-counted pipelining instead of
// SGPR-capacity-limited s_load batches). 1024 blocks -> 4 waves/CU (1/SIMD).
__global__ __launch_bounds__(64, 1)
void realnvp_fwd_pk2(const float* __restrict__ X, const v2f* __restrict__ PW,
                     float* __restrict__ Y, float* __restrict__ LD, int B)
{
    __shared__ float lds[128 * 68];       // 2 rows x 64 active floats, stride 68 (16B-aligned)
    const int tid = threadIdx.x;
    const int r0 = blockIdx.x * 128 + tid;
    const int r1 = r0 + 64;
    if (r1 >= B + 64) return;             // full tile assumed (B % 128 == 0 handled by host)
    float4* A0 = reinterpret_cast<float4*>(lds + tid * 68);
    float4* A1 = reinterpret_cast<float4*>(lds + (64 + tid) * 68);

    int vz = 0;
    asm volatile("" : "+v"(vz));          // opaque zero living in a VGPR

    const float4* x0 = reinterpret_cast<const float4*>(X + (size_t)r0 * DD);
    const float4* x1 = reinterpret_cast<const float4*>(X + (size_t)r1 * DD);
    float xp0[64], xp1[64];
    #pragma unroll
    for (int i = 0; i < 16; ++i){ A0[i] = x0[i]; A1[i] = x1[i]; }
    #pragma unroll
    for (int i = 0; i < 16; ++i){
        float4 v = x0[16+i];
        xp0[4*i]=v.x; xp0[4*i+1]=v.y; xp0[4*i+2]=v.z; xp0[4*i+3]=v.w;
        float4 w = x1[16+i];
        xp1[4*i]=w.x; xp1[4*i+1]=w.y; xp1[4*i+2]=w.z; xp1[4*i+3]=w.w;
    }
    float ld0 = 0.f, ld1 = 0.f;

    #pragma unroll 1
    for (int step = 0; step < NL; ++step){
        const int l = NL - 1 - step;
        const int aOff = (l & 1) ? 0 : 64;
        const int pOff = 64 - aOff;
        const v2f* __restrict__ LB = PW + (size_t)l * L_F2;

        // ---- trunk: h = relu(active @ W1_half + b1), t/s packed, 2 rows ----
        v2f h0[16], h1[16];
        {
            const v2f* __restrict__ b1 = LB + 4864;     // uniform -> SMEM (tiny)
            #pragma unroll
            for (int o = 0; o < 16; ++o){ h0[o] = b1[o]; h1[o] = b1[o]; }
        }
        const float4* __restrict__ w1v =
            reinterpret_cast<const float4*>(LB + (size_t)aOff * 16) + vz;
        #pragma unroll 2
        for (int c = 0; c < 16; ++c){
            float4 a0 = A0[c], a1 = A1[c];
            const float a0q[4] = {a0.x, a0.y, a0.z, a0.w};
            const float a1q[4] = {a1.x, a1.y, a1.z, a1.w};
            #pragma unroll
            for (int q = 0; q < 4; ++q){
                v2f s0 = {a0q[q], a0q[q]};
                v2f s1 = {a1q[q], a1q[q]};
                const float4* __restrict__ wi = w1v + (c*4 + q) * 8;
                #pragma unroll
                for (int m = 0; m < 8; ++m){
                    float4 w = wi[m];
                    v2f wl = flo(w), wh = fhi(w);
                    h0[2*m]   = pk_fma(s0, wl, h0[2*m]);
                    h0[2*m+1] = pk_fma(s0, wh, h0[2*m+1]);
                    h1[2*m]   = pk_fma(s1, wl, h1[2*m]);
                    h1[2*m+1] = pk_fma(s1, wh, h1[2*m+1]);
                }
            }
        }
        #pragma unroll
        for (int o = 0; o < 16; ++o){ h0[o] = pk_relu(h0[o]); h1[o] = pk_relu(h1[o]); }

        // ---- 3 hidden dense16 layers ----
        #pragma unroll 1
        for (int cc = 0; cc < 3; ++cc){
            const float4* __restrict__ w =
                reinterpret_cast<const float4*>(LB + 2048 + cc * 256) + vz;
            const v2f* __restrict__ bb = LB + 4880 + cc * 16;
            v2f o0[16], o1[16];
            #pragma unroll
            for (int j = 0; j < 16; ++j){ o0[j] = bb[j]; o1[j] = bb[j]; }
            #pragma unroll
            for (int i = 0; i < 16; ++i){
                #pragma unroll
                for (int m = 0; m < 8; ++m){
                    float4 wv = w[i*8 + m];
                    v2f wl = flo(wv), wh = fhi(wv);
                    o0[2*m]   = pk_fma(h0[i], wl, o0[2*m]);
                    o0[2*m+1] = pk_fma(h0[i], wh, o0[2*m+1]);
                    o1[2*m]   = pk_fma(h1[i], wl, o1[2*m]);
                    o1[2*m+1] = pk_fma(h1[i], wh, o1[2*m+1]);
                }
            }
            #pragma unroll
            for (int j = 0; j < 16; ++j){ h0[j] = pk_relu(o0[j]); h1[j] = pk_relu(o1[j]); }
        }

        // ---- linear heads + tanh/exp epilogue + fused half-swap ----
        const float4* __restrict__ w5 =
            reinterpret_cast<const float4*>(LB + 2816 + pOff) + vz;    // pOff is even -> aligned
        const v2f* __restrict__ b5 = LB + 4928 + pOff;
        #pragma unroll
        for (int jb = 0; jb < 4; ++jb){
            v2f o0[16], o1[16];
            #pragma unroll
            for (int j = 0; j < 16; ++j){ o0[j] = b5[jb*16 + j]; o1[j] = o0[j]; }
            #pragma unroll
            for (int k = 0; k < 16; ++k){
                #pragma unroll
                for (int m = 0; m < 8; ++m){
                    float4 wv = w5[k*64 + jb*8 + m];
                    v2f wl = flo(wv), wh = fhi(wv);
                    o0[2*m]   = pk_fma(h0[k], wl, o0[2*m]);
                    o0[2*m+1] = pk_fma(h0[k], wh, o0[2*m+1]);
                    o1[2*m]   = pk_fma(h1[k], wl, o1[2*m]);
                    o1[2*m+1] = pk_fma(h1[k], wh, o1[2*m+1]);
                }
            }
            float nw0[16], nw1[16];
            #pragma unroll
            for (int j = 0; j < 16; ++j){
                {
                    float tv = o0[j].x, sv = o0[j].y;
                    float xc = fminf(fmaxf(sv, -15.f), 15.f);
                    float e2 = exp2f(xc * 2.885390081777927f);
                    float se = (e2 - 1.f) * __builtin_amdgcn_rcpf(e2 + 1.f);
                    float e  = exp2f(se * -1.4426950408889634f);
                    nw0[j] = (xp0[jb*16 + j] - tv) * e;
                    ld0 -= se;
                }
                {
                    float tv = o1[j].x, sv = o1[j].y;
                    float xc = fminf(fmaxf(sv, -15.f), 15.f);
                    float e2 = exp2f(xc * 2.885390081777927f);
                    float se = (e2 - 1.f) * __builtin_amdgcn_rcpf(e2 + 1.f);
                    float e  = exp2f(se * -1.4426950408889634f);
                    nw1[j] = (xp1[jb*16 + j] - tv) * e;
                    ld1 -= se;
                }
            }
            #pragma unroll
            for (int q = 0; q < 4; ++q){
                float4 old0 = A0[jb*4 + q];
                A0[jb*4 + q] = (float4){nw0[4*q], nw0[4*q+1], nw0[4*q+2], nw0[4*q+3]};
                xp0[jb*16+4*q+0] = old0.x; xp0[jb*16+4*q+1] = old0.y;
                xp0[jb*16+4*q+2] = old0.z; xp0[jb*16+4*q+3] = old0.w;
                float4 old1 = A1[jb*4 + q];
                A1[jb*4 + q] = (float4){nw1[4*q], nw1[4*q+1], nw1[4*q+2], nw1[4*q+3]};
                xp1[jb*16+4*q+0] = old1.x; xp1[jb*16+4*q+1] = old1.y;
                xp1[jb*16+4*q+2] = old1.z; xp1[jb*16+4*q+3] = old1.w;
            }
        }
    }

    float4* y0 = reinterpret_cast<float4*>(Y + (size_t)r0 * DD);
    float4* y1 = reinterpret_cast<float4*>(Y + (size_t)r1 * DD);
    #pragma unroll
    for (int i = 0; i < 16; ++i){ y0[i] = A0[i]; y1[i] = A1[i]; }
    #pragma unroll
    for (int i = 0; i < 16; ++i){
        y0[16+i] = (float4){xp0[4*i], xp0[4*i+1], xp0[4*i+2], xp0[4*i+3]};
        y1[16+i] = (float4){xp1[4*i], xp1[4*i+1], xp1[4*i+2], xp1[4*i+3]};
    }
    LD[r0] = ld0;
    LD[r1] = ld1;
}

// ---------------- single-row packed kernel (tail / small-B path) ----------------
__global__ __launch_bounds__(64)
void realnvp_fwd_pk(const float* __restrict__ X, const v2f* __restrict__ PW,
                    float* __restrict__ Y, float* __restrict__ LD, int B)
{
    __shared__ float lds[64 * 68];
    const int tid = threadIdx.x;
    const int row = blockIdx.x * 64 + tid;
    if (row >= B) return;
    float4* a4 = reinterpret_cast<float4*>(lds + tid * 68);
    const float4* xr = reinterpret_cast<const float4*>(X + (size_t)row * DD);
    float xp[64];
    #pragma unroll
    for (int i = 0; i < 16; ++i) a4[i] = xr[i];
    #pragma unroll
    for (int i = 0; i < 16; ++i){
        float4 v = xr[16 + i];
        xp[4*i]=v.x; xp[4*i+1]=v.y; xp[4*i+2]=v.z; xp[4*i+3]=v.w;
    }
    float ldv = 0.f;
    #pragma unroll 1
    for (int step = 0; step < NL; ++step){
        const int l = NL - 1 - step;
        const int aOff = (l & 1) ? 0 : 64;
        const int pOff = 64 - aOff;
        const v2f* __restrict__ LB = PW + (size_t)l * L_F2;
        v2f h[16];
        {
            const v2f* b1 = LB + 4864;
            #pragma unroll
            for (int o = 0; o < 16; ++o) h[o] = b1[o];
        }
        const v2f* __restrict__ w1 = LB + aOff * 16;
        #pragma unroll 2
        for (int c = 0; c < 16; ++c){
            float4 av = a4[c];
            const v2f* wc = w1 + c * 64;
            v2f s0={av.x,av.x}, s1={av.y,av.y}, s2={av.z,av.z}, s3={av.w,av.w};
            #pragma unroll
            for (int o = 0; o < 16; ++o){
                h[o] = pk_fma(s0, wc[o],    h[o]);
                h[o] = pk_fma(s1, wc[16+o], h[o]);
                h[o] = pk_fma(s2, wc[32+o], h[o]);
                h[o] = pk_fma(s3, wc[48+o], h[o]);
            }
        }
        #pragma unroll
        for (int o = 0; o < 16; ++o) h[o] = pk_relu(h[o]);
        #pragma unroll 1
        for (int cc = 0; cc < 3; ++cc){
            const v2f* w = LB + 2048 + cc * 256;
            const v2f* b = LB + 4880 + cc * 16;
            v2f o_[16];
            #pragma unroll
            for (int j = 0; j < 16; ++j) o_[j] = b[j];
            #pragma unroll
            for (int i = 0; i < 16; ++i){
                #pragma unroll
                for (int j = 0; j < 16; ++j) o_[j] = pk_fma(h[i], w[i*16+j], o_[j]);
            }
            #pragma unroll
            for (int j = 0; j < 16; ++j) h[j] = pk_relu(o_[j]);
        }
        const v2f* __restrict__ w5 = LB + 2816 + pOff;
        const v2f* __restrict__ b5 = LB + 4928 + pOff;
        #pragma unroll
        for (int jb = 0; jb < 4; ++jb){
            v2f o_[16];
            #pragma unroll
            for (int j = 0; j < 16; ++j) o_[j] = b5[jb*16+j];
            #pragma unroll
            for (int k = 0; k < 16; ++k){
                #pragma unroll
                for (int j = 0; j < 16; ++j) o_[j] = pk_fma(h[k], w5[k*128+jb*16+j], o_[j]);
            }
            float nw[16];
            #pragma unroll
            for (int j = 0; j < 16; ++j){
                float tv = o_[j].x, sv = o_[j].y;
                float xc = fminf(fmaxf(sv, -15.f), 15.f);
                float e2 = exp2f(xc * 2.885390081777927f);
                float se = (e2 - 1.f) * __builtin_amdgcn_rcpf(e2 + 1.f);
                float e  = exp2f(se * -1.4426950408889634f);
                nw[j] = (xp[jb*16+j] - tv) * e;
                ldv -= se;
            }
            #pragma unroll
            for (int q = 0; q < 4; ++q){
                float4 oldc = a4[jb*4+q];
                a4[jb*4+q] = (float4){nw[4*q], nw[4*q+1], nw[4*q+2], nw[4*q+3]};
                xp[jb*16+4*q+0]=oldc.x; xp[jb*16+4*q+1]=oldc.y;
                xp[jb*16+4*q+2]=oldc.z; xp[jb*16+4*q+3]=oldc.w;
            }
        }
    }
    float4* yr = reinterpret_cast<float4*>(Y + (size_t)row * DD);
    #pragma unroll
    for (int i = 0; i < 16; ++i) yr[i] = a4[i];
    #pragma unroll
    for (int i = 0; i < 16; ++i)
        yr[16+i] = (float4){xp[4*i], xp[4*i+1], xp[4*i+2], xp[4*i+3]};
    LD[row] = ldv;
}

extern "C" void kernel_launch(void* const* d_in, const int* in_sizes, int n_in,
                              void* d_out, int out_size, void* d_ws, size_t ws_size,
                              hipStream_t stream)
{
    const float* X   = (const float*)d_in[0];
    const float* tW1 = (const float*)d_in[2];  const float* tb1 = (const float*)d_in[3];
    const float* tW2 = (const float*)d_in[4];  const float* tb2 = (const float*)d_in[5];
    const float* tW3 = (const float*)d_in[6];  const float* tb3 = (const float*)d_in[7];
    const float* tW4 = (const float*)d_in[8];  const float* tb4 = (const float*)d_in[9];
    const float* tW5 = (const float*)d_in[10]; const float* tb5 = (const float*)d_in[11];
    const float* sW1 = (const float*)d_in[12]; const float* sb1 = (const float*)d_in[13];
    const float* sW2 = (const float*)d_in[14]; const float* sb2 = (const float*)d_in[15];
    const float* sW3 = (const float*)d_in[16]; const float* sb3 = (const float*)d_in[17];
    const float* sW4 = (const float*)d_in[18]; const float* sb4 = (const float*)d_in[19];
    const float* sW5 = (const float*)d_in[20]; const float* sb5 = (const float*)d_in[21];

    const int B = in_sizes[0] / DD;
    float* Y  = (float*)d_out;
    float* LD = Y + (size_t)B * DD;

    v2f* pw = (v2f*)d_ws;
    hipLaunchKernelGGL(pack_weights, dim3(NL), dim3(256), 0, stream,
                       tW1, sW1, tW2, sW2, tW3, sW3, tW4, sW4, tW5, sW5,
                       tb1, sb1, tb2, sb2, tb3, sb3, tb4, sb4, tb5, sb5, pw);

    const int Bmain = (B / 128) * 128;
    if (Bmain > 0)
        hipLaunchKernelGGL(realnvp_fwd_pk2, dim3(Bmain / 128), dim3(64), 0, stream,
                           X, pw, Y, LD, Bmain);
    const int tail = B - Bmain;
    if (tail > 0)
        hipLaunchKernelGGL(realnvp_fwd_pk, dim3((tail + 63) / 64), dim3(64), 0, stream,
                           X + (size_t)Bmain * DD, pw, Y + (size_t)Bmain * DD, LD + Bmain, tail);
}

// Round 4
// 138.646 us; speedup vs baseline: 3.6477x; 3.6477x over previous
//
#include <hip/hip_runtime.h>
#include <math.h>

#define NL 6
#define DD 128

typedef __bf16 bf16x8 __attribute__((ext_vector_type(8)));
typedef float  f32x16 __attribute__((ext_vector_type(16)));

// Packed per-(layer,net) block layout (bytes):
//   frag f*1024, f=0..8 : A-fragments, 64 lanes x 16B, lane order
//       f 0..3  trunk  A_j[m][k]=W1[aOff+16j+8h+e][m]   (m<16 real, else 0)
//       f 4..6  hidden A[m][k]  =W{2,3,4}[8h+e][m]      (m<16 real, else 0)
//       f 7..8  head_c A[m][k]  =W5[8h+e][pOff+32c+m]   (all m real)
//   9216 + v*64 + h*32 : bias b{1..4}[v], 8 f32 in D-reg order (regs 0..7)
//   9472 + (c*2+h)*64  : bias b5 chunk c, 16 f32 in D-reg order
#define NET_STRIDE 9728
#define OFF_B14    9216
#define OFF_B5     9472

// ---------- helpers ----------
static __device__ __forceinline__ unsigned cvt_pk_bf16(float lo, float hi){
    unsigned r;
    asm("v_cvt_pk_bf16_f32 %0, %1, %2" : "=v"(r) : "v"(lo), "v"(hi));
    return r;
}

static __device__ __forceinline__ f32x16 mfma32(bf16x8 a, bf16x8 b, f32x16 c){
    return __builtin_amdgcn_mfma_f32_32x32x16_bf16(a, b, c, 0, 0, 0);
}

// own/snd are the 2 packed u32 (4 bf16) this lane owns / must send to its
// h-partner (lane ^ 32). Result B-frag: elems 0-3 = h_src0 data, 4-7 = h_src1.
static __device__ __forceinline__ bf16x8 xchg_assemble(unsigned own0, unsigned own1,
                                                       unsigned snd0, unsigned snd1, int h){
    unsigned r0 = (unsigned)__shfl_xor((int)snd0, 32, 64);
    unsigned r1 = (unsigned)__shfl_xor((int)snd1, 32, 64);
    int4 v;
    v.x = (int)(h ? r0 : own0);
    v.y = (int)(h ? r1 : own1);
    v.z = (int)(h ? own0 : r0);
    v.w = (int)(h ? own1 : r1);
    return __builtin_bit_cast(bf16x8, v);
}

// D regs 0..7 (feats m=4h+r and 8+4h+r) -> relu -> B-frag (K=16) for next layer
static __device__ __forceinline__ bf16x8 dreg_to_B(f32x16 d, int h){
    float d0 = fmaxf(d[0], 0.f), d1 = fmaxf(d[1], 0.f);
    float d2 = fmaxf(d[2], 0.f), d3 = fmaxf(d[3], 0.f);
    float d4 = fmaxf(d[4], 0.f), d5 = fmaxf(d[5], 0.f);
    float d6 = fmaxf(d[6], 0.f), d7 = fmaxf(d[7], 0.f);
    unsigned a0 = cvt_pk_bf16(d0, d1), a1 = cvt_pk_bf16(d2, d3);   // grpA: feats 4h..4h+3
    unsigned b0 = cvt_pk_bf16(d4, d5), b1 = cvt_pk_bf16(d6, d7);   // grpB: feats 8+4h..
    unsigned own0 = h ? b0 : a0, own1 = h ? b1 : a1;               // grp[h]
    unsigned snd0 = h ? a0 : b0, snd1 = h ? a1 : b1;               // grp[1-h]
    return xchg_assemble(own0, own1, snd0, snd1, h);
}

static __device__ __forceinline__ bf16x8 load_frag(const unsigned char* nb, int f, int lane){
    return ((const bf16x8*)(nb + f * 1024))[lane];
}
static __device__ __forceinline__ f32x16 load_bias14(const unsigned char* nb, int v, int h){
    const float4* p = (const float4*)(nb + OFF_B14 + v * 64 + h * 32);
    float4 lo = p[0], hi = p[1];
    f32x16 c = {lo.x, lo.y, lo.z, lo.w, hi.x, hi.y, hi.z, hi.w,
                0.f, 0.f, 0.f, 0.f, 0.f, 0.f, 0.f, 0.f};
    return c;
}
static __device__ __forceinline__ f32x16 load_bias5(const unsigned char* nb, int c, int h){
    const float4* p = (const float4*)(nb + OFF_B5 + (c * 2 + h) * 64);
    float4 a = p[0], b = p[1], cc = p[2], dd = p[3];
    f32x16 r = {a.x, a.y, a.z, a.w, b.x, b.y, b.z, b.w,
                cc.x, cc.y, cc.z, cc.w, dd.x, dd.y, dd.z, dd.w};
    return r;
}

// ---------- pack kernel ----------
static __device__ __forceinline__ unsigned short f2bf_rne(float f){
    unsigned u = __float_as_uint(f);
    u += 0x7FFFu + ((u >> 16) & 1u);
    return (unsigned short)(u >> 16);
}

__global__ void pack_frags(
    const float* __restrict__ tW1, const float* __restrict__ tb1,
    const float* __restrict__ tW2, const float* __restrict__ tb2,
    const float* __restrict__ tW3, const float* __restrict__ tb3,
    const float* __restrict__ tW4, const float* __restrict__ tb4,
    const float* __restrict__ tW5, const float* __restrict__ tb5,
    const float* __restrict__ sW1, const float* __restrict__ sb1,
    const float* __restrict__ sW2, const float* __restrict__ sb2,
    const float* __restrict__ sW3, const float* __restrict__ sb3,
    const float* __restrict__ sW4, const float* __restrict__ sb4,
    const float* __restrict__ sW5, const float* __restrict__ sb5,
    unsigned char* __restrict__ pw)
{
    const int l = blockIdx.x;
    const int aOff = (l & 1) ? 0 : 64;
    const int pOff = 64 - aOff;
    for (int p = 0; p < 2; ++p){
        const float* W1 = p ? sW1 : tW1;  const float* W2 = p ? sW2 : tW2;
        const float* W3 = p ? sW3 : tW3;  const float* W4 = p ? sW4 : tW4;
        const float* W5 = p ? sW5 : tW5;
        const float* b1 = p ? sb1 : tb1;  const float* b2 = p ? sb2 : tb2;
        const float* b3 = p ? sb3 : tb3;  const float* b4 = p ? sb4 : tb4;
        const float* b5 = p ? sb5 : tb5;
        unsigned char* base = pw + ((size_t)l * 2 + p) * NET_STRIDE;

        for (int t = threadIdx.x; t < 576; t += blockDim.x){
            int f = t >> 6, lane = t & 63;
            int m = lane & 31, h = lane >> 5;
            unsigned short v[8];
            if (f < 4){
                #pragma unroll
                for (int e = 0; e < 8; ++e){
                    float x = (m < 16) ? W1[l*2048 + (aOff + 16*f + 8*h + e)*16 + m] : 0.f;
                    v[e] = f2bf_rne(x);
                }
            } else if (f < 7){
                const float* W = (f == 4) ? W2 : (f == 5) ? W3 : W4;
                #pragma unroll
                for (int e = 0; e < 8; ++e){
                    float x = (m < 16) ? W[l*256 + (8*h + e)*16 + m] : 0.f;
                    v[e] = f2bf_rne(x);
                }
            } else {
                int c = f - 7;
                #pragma unroll
                for (int e = 0; e < 8; ++e){
                    float x = W5[l*2048 + (8*h + e)*128 + (pOff + 32*c + m)];
                    v[e] = f2bf_rne(x);
                }
            }
            int4 o;
            o.x = (int)((unsigned)v[0] | ((unsigned)v[1] << 16));
            o.y = (int)((unsigned)v[2] | ((unsigned)v[3] << 16));
            o.z = (int)((unsigned)v[4] | ((unsigned)v[5] << 16));
            o.w = (int)((unsigned)v[6] | ((unsigned)v[7] << 16));
            ((int4*)(base + f * 1024))[lane] = o;
        }
        for (int t = threadIdx.x; t < 128; t += blockDim.x){
            if (t < 64){
                int vv = t >> 4, h = (t >> 3) & 1, r = t & 7;
                int m = (r & 3) + 8 * (r >> 2) + 4 * h;
                const float* bb = (vv == 0) ? b1 : (vv == 1) ? b2 : (vv == 2) ? b3 : b4;
                ((float*)(base + OFF_B14 + vv * 64 + h * 32))[r] = bb[l*16 + m];
            } else {
                int u = t - 64;
                int c = u >> 5, h = (u >> 4) & 1, r = u & 15;
                int m = (r & 3) + 8 * (r >> 2) + 4 * h;
                ((float*)(base + OFF_B5 + (c * 2 + h) * 64))[r] = b5[l*128 + pOff + 32*c + m];
            }
        }
    }
}

// ---------- main kernel: one 32-row tile per wave, swapped-operand MFMA ----------
__global__ __launch_bounds__(256, 2)
void realnvp_mfma(const float* __restrict__ X, const unsigned char* __restrict__ PW,
                  float* __restrict__ Y, float* __restrict__ LD, int B)
{
    const int lane = threadIdx.x & 63;
    const int wid  = blockIdx.x * (blockDim.x >> 6) + (threadIdx.x >> 6);
    const int n = lane & 31, h = lane >> 5;
    const int row = wid * 32 + n;
    if (wid * 32 >= B) return;
    const int rowc = (row < B) ? row : (B - 1);

    // x halves, f32, D-layout: index g = c*4+q holds feats half + 32c+8q+4h+(0..3)
    const float* xrow = X + (size_t)rowc * DD;
    float4 xa[8], xp[8];               // active (l=5: feats [0,64)), passive ([64,128))
    #pragma unroll
    for (int g = 0; g < 8; ++g){
        int c = g >> 2, q = g & 3;
        xa[g] = *(const float4*)(xrow + 32*c + 8*q + 4*h);
        xp[g] = *(const float4*)(xrow + 64 + 32*c + 8*q + 4*h);
    }
    float sacc = 0.f;

    #pragma unroll 1
    for (int step = 0; step < NL; ++step){
        const int l = NL - 1 - step;
        const unsigned char* bt = PW + (size_t)(l * 2 + 0) * NET_STRIDE;
        const unsigned char* bs = PW + (size_t)(l * 2 + 1) * NET_STRIDE;

        // ---- trunk B-frags from xa (shared by both nets) ----
        unsigned pk[8][2];
        #pragma unroll
        for (int g = 0; g < 8; ++g){
            pk[g][0] = cvt_pk_bf16(xa[g].x, xa[g].y);
            pk[g][1] = cvt_pk_bf16(xa[g].z, xa[g].w);
        }
        bf16x8 Bt[4];
        #pragma unroll
        for (int j = 0; j < 4; ++j){
            int c  = j >> 1;
            int qo = (2*j + h) & 3;
            int qs = (2*j + 1 - h) & 3;
            Bt[j] = xchg_assemble(pk[c*4+qo][0], pk[c*4+qo][1],
                                  pk[c*4+qs][0], pk[c*4+qs][1], h);
        }

        // ---- trunk MFMAs (K=64 as 4xK16), bias via C ----
        f32x16 at = load_bias14(bt, 0, h);
        f32x16 as = load_bias14(bs, 0, h);
        #pragma unroll
        for (int j = 0; j < 4; ++j){
            at = mfma32(load_frag(bt, j, lane), Bt[j], at);
            as = mfma32(load_frag(bs, j, lane), Bt[j], as);
        }

        // ---- 3 hidden layers ----
        #pragma unroll
        for (int cc = 0; cc < 3; ++cc){
            bf16x8 Bh_t = dreg_to_B(at, h);
            bf16x8 Bh_s = dreg_to_B(as, h);
            f32x16 nt = load_bias14(bt, cc + 1, h);
            f32x16 ns = load_bias14(bs, cc + 1, h);
            nt = mfma32(load_frag(bt, 4 + cc, lane), Bh_t, nt);
            ns = mfma32(load_frag(bs, 4 + cc, lane), Bh_s, ns);
            at = nt; as = ns;
        }

        // ---- heads: 2 chunks of 32 passive feats each ----
        bf16x8 Bf_t = dreg_to_B(at, h);
        bf16x8 Bf_s = dreg_to_B(as, h);
        f32x16 tD0 = mfma32(load_frag(bt, 7, lane), Bf_t, load_bias5(bt, 0, h));
        f32x16 tD1 = mfma32(load_frag(bt, 8, lane), Bf_t, load_bias5(bt, 1, h));
        f32x16 sD0 = mfma32(load_frag(bs, 7, lane), Bf_s, load_bias5(bs, 0, h));
        f32x16 sD1 = mfma32(load_frag(bs, 8, lane), Bf_s, load_bias5(bs, 1, h));

        // ---- epilogue: y = (xp - t) * exp(-tanh_s); swap halves ----
        #pragma unroll
        for (int c = 0; c < 2; ++c){
            f32x16 tD = c ? tD1 : tD0;
            f32x16 sD = c ? sD1 : sD0;
            #pragma unroll
            for (int q = 0; q < 4; ++q){
                float nv[4];
                float4 xpv = xp[c*4 + q];
                float xq[4] = {xpv.x, xpv.y, xpv.z, xpv.w};
                #pragma unroll
                for (int rr = 0; rr < 4; ++rr){
                    const int r = q * 4 + rr;
                    float tv = tD[r], sv = sD[r];
                    float xc = fminf(fmaxf(sv, -15.f), 15.f);
                    float e2 = exp2f(xc * 2.885390081777927f);              // e^(2s)
                    float se = (e2 - 1.f) * __builtin_amdgcn_rcpf(e2 + 1.f); // tanh(s)
                    float e  = exp2f(se * -1.4426950408889634f);            // exp(-s)
                    nv[rr] = (xq[rr] - tv) * e;
                    sacc += se;
                }
                float4 olda = xa[c*4 + q];
                xa[c*4 + q] = (float4){nv[0], nv[1], nv[2], nv[3]};
                xp[c*4 + q] = olda;
            }
        }
    }

    // final: xa = feats [0,64), xp = feats [64,128)
    if (row < B){
        float* yrow = Y + (size_t)row * DD;
        #pragma unroll
        for (int g = 0; g < 8; ++g){
            int c = g >> 2, q = g & 3;
            *(float4*)(yrow + 32*c + 8*q + 4*h)      = xa[g];
            *(float4*)(yrow + 64 + 32*c + 8*q + 4*h) = xp[g];
        }
        float ls = sacc + __shfl_xor(sacc, 32, 64);
        if (h == 0) LD[row] = -ls;
    }
}

extern "C" void kernel_launch(void* const* d_in, const int* in_sizes, int n_in,
                              void* d_out, int out_size, void* d_ws, size_t ws_size,
                              hipStream_t stream)
{
    const float* X   = (const float*)d_in[0];
    const float* tW1 = (const float*)d_in[2];  const float* tb1 = (const float*)d_in[3];
    const float* tW2 = (const float*)d_in[4];  const float* tb2 = (const float*)d_in[5];
    const float* tW3 = (const float*)d_in[6];  const float* tb3 = (const float*)d_in[7];
    const float* tW4 = (const float*)d_in[8];  const float* tb4 = (const float*)d_in[9];
    const float* tW5 = (const float*)d_in[10]; const float* tb5 = (const float*)d_in[11];
    const float* sW1 = (const float*)d_in[12]; const float* sb1 = (const float*)d_in[13];
    const float* sW2 = (const float*)d_in[14]; const float* sb2 = (const float*)d_in[15];
    const float* sW3 = (const float*)d_in[16]; const float* sb3 = (const float*)d_in[17];
    const float* sW4 = (const float*)d_in[18]; const float* sb4 = (const float*)d_in[19];
    const float* sW5 = (const float*)d_in[20]; const float* sb5 = (const float*)d_in[21];

    const int B = in_sizes[0] / DD;
    float* Y  = (float*)d_out;
    float* LD = Y + (size_t)B * DD;

    unsigned char* pw = (unsigned char*)d_ws;   // needs 12*9728 = 116,736 B
    hipLaunchKernelGGL(pack_frags, dim3(NL), dim3(256), 0, stream,
                       tW1, tb1, tW2, tb2, tW3, tb3, tW4, tb4, tW5, tb5,
                       sW1, sb1, sW2, sb2, sW3, sb3, sW4, sb4, sW5, sb5, pw);

    const int nwaves = (B + 31) / 32;
    const int blocks = (nwaves + 3) / 4;        // 4 waves (256 thr) per block
    hipLaunchKernelGGL(realnvp_mfma, dim3(blocks), dim3(256), 0, stream,
                       X, pw, Y, LD, B);
}

// Round 6
// 90.863 us; speedup vs baseline: 5.5659x; 1.5259x over previous
//
#include <hip/hip_runtime.h>
#include <math.h>

#define NL 6
#define DD 128

typedef __bf16 bf16x8 __attribute__((ext_vector_type(8)));
typedef float  f32x16 __attribute__((ext_vector_type(16)));

// Packed per-(layer,net) block layout (bytes):
//   frag f*1024, f=0..8 : A-fragments, 64 lanes x 16B, lane order (same as r4)
//   9216 + (v*2+h)*64   : bias b{1..4}[v], 16 f32 D-layout record (upper 8 = 0)
//   9728 + (c*2+h)*64   : bias b5 chunk c, 16 f32 D-layout record
#define NET_STRIDE 9984
#define OFF_B14    9216
#define OFF_B5     9728

// ---------- helpers ----------
static __device__ __forceinline__ unsigned cvt_pk_bf16(float lo, float hi){
    unsigned r;
    asm("v_cvt_pk_bf16_f32 %0, %1, %2" : "=v"(r) : "v"(lo), "v"(hi));
    return r;
}
// V_PERMLANE32_SWAP_B32 semantics (CDNA4): VDST lanes [32:63] <-> SRC0 lanes [0:31].
// So swap32(a, b) performs: a_hi <-> b_lo, giving
//   a' = [a_lo | b_from_h0_partner],  b' = [a_from_h1_partner | b_hi]
static __device__ __forceinline__ void swap32(unsigned &dst, unsigned &src){
    asm("v_permlane32_swap_b32 %0, %1" : "+v"(dst), "+v"(src));
}
static __device__ __forceinline__ f32x16 mfma32(bf16x8 a, bf16x8 b, f32x16 c){
    return __builtin_amdgcn_mfma_f32_32x32x16_bf16(a, b, c, 0, 0, 0);
}
static __device__ __forceinline__ bf16x8 frag4(unsigned w0, unsigned w1, unsigned w2, unsigned w3){
    int4 v; v.x = (int)w0; v.y = (int)w1; v.z = (int)w2; v.w = (int)w3;
    return __builtin_bit_cast(bf16x8, v);
}
// relu(D regs 0..7) -> B-frag (K=16). Equivalent to r4's verified shfl+select path:
// h=0 lane ends with [own a | partner a] = feats 0..7; h=1 with [partner b | own b] = feats 8..15.
static __device__ __forceinline__ bf16x8 dreg_to_B(f32x16 d){
    unsigned a0 = cvt_pk_bf16(fmaxf(d[0], 0.f), fmaxf(d[1], 0.f));
    unsigned a1 = cvt_pk_bf16(fmaxf(d[2], 0.f), fmaxf(d[3], 0.f));
    unsigned b0 = cvt_pk_bf16(fmaxf(d[4], 0.f), fmaxf(d[5], 0.f));
    unsigned b1 = cvt_pk_bf16(fmaxf(d[6], 0.f), fmaxf(d[7], 0.f));
    swap32(a0, b0);     // a0_hi <-> b0_lo
    swap32(a1, b1);
    return frag4(a0, a1, b0, b1);
}
static __device__ __forceinline__ bf16x8 load_frag(const unsigned char* nb, int f, int lane){
    return ((const bf16x8*)(nb + f * 1024))[lane];
}
static __device__ __forceinline__ f32x16 load_b14(const unsigned char* nb, int v, int h){
    return *(const f32x16*)(nb + OFF_B14 + (v * 2 + h) * 64);
}
static __device__ __forceinline__ f32x16 load_b5(const unsigned char* nb, int c, int h){
    return *(const f32x16*)(nb + OFF_B5 + (c * 2 + h) * 64);
}

// ---------- pack kernel ----------
static __device__ __forceinline__ unsigned short f2bf_rne(float f){
    unsigned u = __float_as_uint(f);
    u += 0x7FFFu + ((u >> 16) & 1u);
    return (unsigned short)(u >> 16);
}

__global__ void pack_frags(
    const float* __restrict__ tW1, const float* __restrict__ tb1,
    const float* __restrict__ tW2, const float* __restrict__ tb2,
    const float* __restrict__ tW3, const float* __restrict__ tb3,
    const float* __restrict__ tW4, const float* __restrict__ tb4,
    const float* __restrict__ tW5, const float* __restrict__ tb5,
    const float* __restrict__ sW1, const float* __restrict__ sb1,
    const float* __restrict__ sW2, const float* __restrict__ sb2,
    const float* __restrict__ sW3, const float* __restrict__ sb3,
    const float* __restrict__ sW4, const float* __restrict__ sb4,
    const float* __restrict__ sW5, const float* __restrict__ sb5,
    unsigned char* __restrict__ pw)
{
    const int l = blockIdx.x;
    const int aOff = (l & 1) ? 0 : 64;
    const int pOff = 64 - aOff;
    for (int p = 0; p < 2; ++p){
        const float* W1 = p ? sW1 : tW1;  const float* W2 = p ? sW2 : tW2;
        const float* W3 = p ? sW3 : tW3;  const float* W4 = p ? sW4 : tW4;
        const float* W5 = p ? sW5 : tW5;
        const float* b1 = p ? sb1 : tb1;  const float* b2 = p ? sb2 : tb2;
        const float* b3 = p ? sb3 : tb3;  const float* b4 = p ? sb4 : tb4;
        const float* b5 = p ? sb5 : tb5;
        unsigned char* base = pw + ((size_t)l * 2 + p) * NET_STRIDE;

        for (int t = threadIdx.x; t < 576; t += blockDim.x){
            int f = t >> 6, lane = t & 63;
            int m = lane & 31, h = lane >> 5;
            unsigned short v[8];
            if (f < 4){
                #pragma unroll
                for (int e = 0; e < 8; ++e){
                    float x = (m < 16) ? W1[l*2048 + (aOff + 16*f + 8*h + e)*16 + m] : 0.f;
                    v[e] = f2bf_rne(x);
                }
            } else if (f < 7){
                const float* W = (f == 4) ? W2 : (f == 5) ? W3 : W4;
                #pragma unroll
                for (int e = 0; e < 8; ++e){
                    float x = (m < 16) ? W[l*256 + (8*h + e)*16 + m] : 0.f;
                    v[e] = f2bf_rne(x);
                }
            } else {
                int c = f - 7;
                #pragma unroll
                for (int e = 0; e < 8; ++e){
                    float x = W5[l*2048 + (8*h + e)*128 + (pOff + 32*c + m)];
                    v[e] = f2bf_rne(x);
                }
            }
            int4 o;
            o.x = (int)((unsigned)v[0] | ((unsigned)v[1] << 16));
            o.y = (int)((unsigned)v[2] | ((unsigned)v[3] << 16));
            o.z = (int)((unsigned)v[4] | ((unsigned)v[5] << 16));
            o.w = (int)((unsigned)v[6] | ((unsigned)v[7] << 16));
            ((int4*)(base + f * 1024))[lane] = o;
        }
        // biases as full 16-f32 D-layout records
        for (int t = threadIdx.x; t < 192; t += blockDim.x){
            if (t < 128){
                int vv = t >> 5, h = (t >> 4) & 1, r = t & 15;
                const float* bb = (vv == 0) ? b1 : (vv == 1) ? b2 : (vv == 2) ? b3 : b4;
                float val = 0.f;
                if (r < 8){ int m = (r & 3) + 8 * (r >> 2) + 4 * h; val = bb[l*16 + m]; }
                ((float*)(base + OFF_B14 + (vv * 2 + h) * 64))[r] = val;
            } else {
                int u = t - 128;
                int c = u >> 5, h = (u >> 4) & 1, r = u & 15;
                int m = (r & 3) + 8 * (r >> 2) + 4 * h;
                ((float*)(base + OFF_B5 + (c * 2 + h) * 64))[r] = b5[l*128 + pOff + 32*c + m];
            }
        }
    }
}

// ---------- main kernel ----------
__global__ __launch_bounds__(256, 4)
void realnvp_mfma2(const float* __restrict__ X, const unsigned char* __restrict__ PW,
                   float* __restrict__ Y, float* __restrict__ LD, int B)
{
    __shared__ float4 xpl[8][256];          // passive half, lane-private slots (32 KB)
    const int tid  = threadIdx.x;
    const int lane = tid & 63;
    const int wid  = blockIdx.x * 4 + (tid >> 6);
    const int n = lane & 31, h = lane >> 5;
    const int row = wid * 32 + n;
    if (wid * 32 >= B) return;
    const int rowc = (row < B) ? row : (B - 1);

    const float* xrow = X + (size_t)rowc * DD;
    float4 xa[8];                            // active half (f32, regs)
    #pragma unroll
    for (int g = 0; g < 8; ++g){
        int c = g >> 2, q = g & 3;
        xa[g]        = *(const float4*)(xrow + 32*c + 8*q + 4*h);
        xpl[g][tid]  = *(const float4*)(xrow + 64 + 32*c + 8*q + 4*h);
    }
    float sacc = 0.f;

    #pragma unroll 1
    for (int step = 0; step < NL; ++step){
        const int l = NL - 1 - step;
        const unsigned char* bt = PW + (size_t)(l * 2 + 0) * NET_STRIDE;
        const unsigned char* bs = PW + (size_t)(l * 2 + 1) * NET_STRIDE;

        // ---- trunk B-frags from xa (shared by both nets), permlane exchange ----
        unsigned p0[8], p1[8];
        #pragma unroll
        for (int g = 0; g < 8; ++g){
            p0[g] = cvt_pk_bf16(xa[g].x, xa[g].y);
            p1[g] = cvt_pk_bf16(xa[g].z, xa[g].w);
        }
        bf16x8 Bt[4];
        #pragma unroll
        for (int j = 0; j < 4; ++j){
            unsigned a0 = p0[2*j], a1 = p1[2*j];       // even-q group
            unsigned b0 = p0[2*j+1], b1 = p1[2*j+1];   // odd-q group
            swap32(a0, b0);                            // a_hi <-> b_lo
            swap32(a1, b1);
            Bt[j] = frag4(a0, a1, b0, b1);
        }

        // ---- trunk MFMAs (K=64 as 4xK16), bias via C ----
        f32x16 at = load_b14(bt, 0, h);
        f32x16 as = load_b14(bs, 0, h);
        #pragma unroll
        for (int j = 0; j < 4; ++j){
            at = mfma32(load_frag(bt, j, lane), Bt[j], at);
            as = mfma32(load_frag(bs, j, lane), Bt[j], as);
        }

        // ---- 3 hidden layers ----
        #pragma unroll
        for (int cc = 0; cc < 3; ++cc){
            bf16x8 Bh_t = dreg_to_B(at);
            bf16x8 Bh_s = dreg_to_B(as);
            at = mfma32(load_frag(bt, 4 + cc, lane), Bh_t, load_b14(bt, cc + 1, h));
            as = mfma32(load_frag(bs, 4 + cc, lane), Bh_s, load_b14(bs, cc + 1, h));
        }

        // ---- heads: chunk-serial (c=0 fully, then c=1) to cap register liveness ----
        bf16x8 Bf_t = dreg_to_B(at);
        bf16x8 Bf_s = dreg_to_B(as);
        #pragma unroll
        for (int c = 0; c < 2; ++c){
            f32x16 tD = mfma32(load_frag(bt, 7 + c, lane), Bf_t, load_b5(bt, c, h));
            f32x16 sD = mfma32(load_frag(bs, 7 + c, lane), Bf_s, load_b5(bs, c, h));
            #pragma unroll
            for (int q = 0; q < 4; ++q){
                float4 xpv = xpl[c*4 + q][tid];
                float xq[4] = {xpv.x, xpv.y, xpv.z, xpv.w};
                float nv[4];
                #pragma unroll
                for (int rr = 0; rr < 4; ++rr){
                    const int r = q * 4 + rr;
                    float tv = tD[r], sv = sD[r];
                    float xc = fminf(fmaxf(sv, -15.f), 15.f);
                    float e2 = exp2f(xc * 2.885390081777927f);               // e^(2s)
                    float se = (e2 - 1.f) * __builtin_amdgcn_rcpf(e2 + 1.f); // tanh(s)
                    float e  = exp2f(se * -1.4426950408889634f);             // exp(-s)
                    nv[rr] = (xq[rr] - tv) * e;
                    sacc += se;
                }
                xpl[c*4 + q][tid] = xa[c*4 + q];                 // old active -> passive
                xa[c*4 + q] = (float4){nv[0], nv[1], nv[2], nv[3]};  // new active
            }
        }
    }

    // final: xa = feats [0,64), xpl = feats [64,128)
    if (row < B){
        float* yrow = Y + (size_t)row * DD;
        #pragma unroll
        for (int g = 0; g < 8; ++g){
            int c = g >> 2, q = g & 3;
            *(float4*)(yrow + 32*c + 8*q + 4*h)      = xa[g];
            *(float4*)(yrow + 64 + 32*c + 8*q + 4*h) = xpl[g][tid];
        }
        float ls = sacc + __shfl_xor(sacc, 32, 64);
        if (h == 0) LD[row] = -ls;
    }
}

extern "C" void kernel_launch(void* const* d_in, const int* in_sizes, int n_in,
                              void* d_out, int out_size, void* d_ws, size_t ws_size,
                              hipStream_t stream)
{
    const float* X   = (const float*)d_in[0];
    const float* tW1 = (const float*)d_in[2];  const float* tb1 = (const float*)d_in[3];
    const float* tW2 = (const float*)d_in[4];  const float* tb2 = (const float*)d_in[5];
    const float* tW3 = (const float*)d_in[6];  const float* tb3 = (const float*)d_in[7];
    const float* tW4 = (const float*)d_in[8];  const float* tb4 = (const float*)d_in[9];
    const float* tW5 = (const float*)d_in[10]; const float* tb5 = (const float*)d_in[11];
    const float* sW1 = (const float*)d_in[12]; const float* sb1 = (const float*)d_in[13];
    const float* sW2 = (const float*)d_in[14]; const float* sb2 = (const float*)d_in[15];
    const float* sW3 = (const float*)d_in[16]; const float* sb3 = (const float*)d_in[17];
    const float* sW4 = (const float*)d_in[18]; const float* sb4 = (const float*)d_in[19];
    const float* sW5 = (const float*)d_in[20]; const float* sb5 = (const float*)d_in[21];

    const int B = in_sizes[0] / DD;
    float* Y  = (float*)d_out;
    float* LD = Y + (size_t)B * DD;

    unsigned char* pw = (unsigned char*)d_ws;   // needs 12*9984 = 119,808 B
    hipLaunchKernelGGL(pack_frags, dim3(NL), dim3(256), 0, stream,
                       tW1, tb1, tW2, tb2, tW3, tb3, tW4, tb4, tW5, tb5,
                       sW1, sb1, sW2, sb2, sW3, sb3, sW4, sb4, sW5, sb5, pw);

    const int nwaves = (B + 31) / 32;
    const int blocks = (nwaves + 3) / 4;        // 4 waves (256 thr) per block
    hipLaunchKernelGGL(realnvp_mfma2, dim3(blocks), dim3(256), 0, stream,
                       X, pw, Y, LD, B);
}

// Round 7
// 77.369 us; speedup vs baseline: 6.5367x; 1.1744x over previous
//
#include <hip/hip_runtime.h>
#include <math.h>

#define NL 6
#define DD 128

typedef __bf16 bf16x8 __attribute__((ext_vector_type(8)));
typedef float  f32x4  __attribute__((ext_vector_type(4)));

// Frag file per (layer l, net p), base = (l*2+p)*NET_STRIDE (bytes):
//   [0,2048)    trunk A: 2 K-slices x (64 lanes x 16B)
//   [2048,5120) hidden A: 3 x (64 x 16B)   (slots e>=4 zero)
//   [5120,9216) head  A: 4 chunks x (64 x 16B) (slots e>=4 zero)
// Slot map (consistent in A and B, so internal order cancels):
//   slot(q,e) -> logical k = (e<4) ? 4q+e : 16+4q+(e-4)
#define NET_STRIDE 9216
#define OFF_HID    2048
#define OFF_HEAD   5120

static __device__ __forceinline__ unsigned cvt_pk_bf16(float lo, float hi){
    unsigned r;
    asm("v_cvt_pk_bf16_f32 %0, %1, %2" : "=v"(r) : "v"(lo), "v"(hi));
    return r;
}
static __device__ __forceinline__ f32x4 mfma(bf16x8 a, bf16x8 b, f32x4 c){
    return __builtin_amdgcn_mfma_f32_16x16x32_bf16(a, b, c, 0, 0, 0);
}
static __device__ __forceinline__ bf16x8 frag4(unsigned w0, unsigned w1, unsigned w2, unsigned w3){
    int4 v; v.x=(int)w0; v.y=(int)w1; v.z=(int)w2; v.w=(int)w3;
    return __builtin_bit_cast(bf16x8, v);
}
// relu(D regs) -> B-frag for K=16 layers. D feat = 4q+r matches B slot k=4q+e directly.
static __device__ __forceinline__ bf16x8 dreg_to_B(f32x4 d){
    unsigned w0 = cvt_pk_bf16(fmaxf(d[0],0.f), fmaxf(d[1],0.f));
    unsigned w1 = cvt_pk_bf16(fmaxf(d[2],0.f), fmaxf(d[3],0.f));
    return frag4(w0, w1, 0u, 0u);
}
static __device__ __forceinline__ bf16x8 load_frag(const unsigned char* nb, int off, int lane){
    return *(const bf16x8*)(nb + off + lane * 16);
}

// ---------- pack kernel (weights only; biases are consumed in natural order) ----------
static __device__ __forceinline__ unsigned short f2bf_rne(float f){
    unsigned u = __float_as_uint(f);
    u += 0x7FFFu + ((u >> 16) & 1u);
    return (unsigned short)(u >> 16);
}

__global__ void pack_frags(
    const float* __restrict__ tW1, const float* __restrict__ tW2,
    const float* __restrict__ tW3, const float* __restrict__ tW4,
    const float* __restrict__ tW5,
    const float* __restrict__ sW1, const float* __restrict__ sW2,
    const float* __restrict__ sW3, const float* __restrict__ sW4,
    const float* __restrict__ sW5,
    unsigned char* __restrict__ pw)
{
    const int bx = blockIdx.x;           // = l*2 + p
    const int l = bx >> 1, p = bx & 1;
    const int aOff = (l & 1) ? 0 : 64;
    const int pOff = 64 - aOff;
    const float* W1 = p ? sW1 : tW1;
    const float* W2 = p ? sW2 : tW2;
    const float* W3 = p ? sW3 : tW3;
    const float* W4 = p ? sW4 : tW4;
    const float* W5 = p ? sW5 : tW5;
    unsigned char* base = pw + (size_t)bx * NET_STRIDE;

    for (int t = threadIdx.x; t < 576; t += blockDim.x){
        const int lane = t & 63, m = lane & 15, q = lane >> 4;
        unsigned short v[8];
        unsigned char* dst;
        if (t < 128){                    // trunk: full K=32 slices
            int slice = t >> 6;
            #pragma unroll
            for (int e = 0; e < 8; ++e){
                int sg = (e < 4) ? (4*q + e) : (16 + 4*q + (e - 4));
                v[e] = f2bf_rne(W1[l*2048 + (aOff + 32*slice + sg)*16 + m]);
            }
            dst = base + slice*1024 + lane*16;
        } else if (t < 320){             // hidden: K=16 in slots e<4, zeros above
            int hh = (t - 128) >> 6;
            const float* W = (hh == 0) ? W2 : (hh == 1) ? W3 : W4;
            #pragma unroll
            for (int e = 0; e < 8; ++e)
                v[e] = (e < 4) ? f2bf_rne(W[l*256 + (4*q + e)*16 + m]) : (unsigned short)0;
            dst = base + OFF_HID + hh*1024 + lane*16;
        } else {                         // head chunk c: passive feats pOff+16c+m, natural order
            int c = (t - 320) >> 6;
            #pragma unroll
            for (int e = 0; e < 8; ++e)
                v[e] = (e < 4) ? f2bf_rne(W5[l*2048 + (4*q + e)*128 + pOff + 16*c + m])
                               : (unsigned short)0;
            dst = base + OFF_HEAD + c*1024 + lane*16;
        }
        int4 o;
        o.x = (int)((unsigned)v[0] | ((unsigned)v[1] << 16));
        o.y = (int)((unsigned)v[2] | ((unsigned)v[3] << 16));
        o.z = (int)((unsigned)v[4] | ((unsigned)v[5] << 16));
        o.w = (int)((unsigned)v[6] | ((unsigned)v[7] << 16));
        *(int4*)dst = o;
    }
}

// ---------- main kernel: 16 rows/wave, 16x16x32 MFMA, zero cross-lane dataflow ----------
// x-state layout per lane (q = lane>>4, n = lane&15 = row):
//   slot j (0..3) = float4 of feats (half + 16*j + 4*q + 0..3)  -- matches B k=4q+e and D feat=4q+r
__global__ __launch_bounds__(256, 6)
void realnvp_mfma16(const float* __restrict__ X, const unsigned char* __restrict__ PW,
    const float* __restrict__ tb1, const float* __restrict__ tb2,
    const float* __restrict__ tb3, const float* __restrict__ tb4,
    const float* __restrict__ tb5,
    const float* __restrict__ sb1, const float* __restrict__ sb2,
    const float* __restrict__ sb3, const float* __restrict__ sb4,
    const float* __restrict__ sb5,
    float* __restrict__ Y, float* __restrict__ LD, int B)
{
    __shared__ float4 xpl[4][256];       // passive half (16 KB)
    const int tid  = threadIdx.x;
    const int lane = tid & 63;
    const int wid  = blockIdx.x * 4 + (tid >> 6);
    const int q = lane >> 4, n = lane & 15;
    const int row = wid * 16 + n;
    if (wid * 16 >= B) return;
    const int rowc = (row < B) ? row : (B - 1);

    const float* xrow = X + (size_t)rowc * DD;
    float4 xa[4];
    #pragma unroll
    for (int j = 0; j < 4; ++j){
        const int off = 16*j + 4*q;
        xa[j]       = *(const float4*)(xrow + off);        // first layer l=5: active = [0,64)
        xpl[j][tid] = *(const float4*)(xrow + 64 + off);
    }
    float sacc = 0.f;

    #pragma unroll 1
    for (int step = 0; step < NL; ++step){
        const int l = NL - 1 - step;
        const int pOff = (l & 1) ? 64 : 0;
        const unsigned char* bt = PW + (size_t)(l * 2 + 0) * NET_STRIDE;
        const unsigned char* bs = PW + (size_t)(l * 2 + 1) * NET_STRIDE;

        // ---- trunk B-frags straight from xa (slot map matches x layout) ----
        bf16x8 Bt0 = frag4(cvt_pk_bf16(xa[0].x, xa[0].y), cvt_pk_bf16(xa[0].z, xa[0].w),
                           cvt_pk_bf16(xa[1].x, xa[1].y), cvt_pk_bf16(xa[1].z, xa[1].w));
        bf16x8 Bt1 = frag4(cvt_pk_bf16(xa[2].x, xa[2].y), cvt_pk_bf16(xa[2].z, xa[2].w),
                           cvt_pk_bf16(xa[3].x, xa[3].y), cvt_pk_bf16(xa[3].z, xa[3].w));

        // ---- trunk: K=64 as 2 x K32, bias via C (natural order: b[4q+r]) ----
        f32x4 at = *(const f32x4*)(tb1 + l*16 + 4*q);
        f32x4 as = *(const f32x4*)(sb1 + l*16 + 4*q);
        at = mfma(load_frag(bt, 0,    lane), Bt0, at);
        at = mfma(load_frag(bt, 1024, lane), Bt1, at);
        as = mfma(load_frag(bs, 0,    lane), Bt0, as);
        as = mfma(load_frag(bs, 1024, lane), Bt1, as);

        // ---- 3 hidden 16x16 layers (K=16 via zeroed upper slots) ----
        #pragma unroll
        for (int hh = 0; hh < 3; ++hh){
            const float* hbt = (hh == 0) ? tb2 : (hh == 1) ? tb3 : tb4;
            const float* hbs = (hh == 0) ? sb2 : (hh == 1) ? sb3 : sb4;
            bf16x8 Bh_t = dreg_to_B(at);
            bf16x8 Bh_s = dreg_to_B(as);
            at = mfma(load_frag(bt, OFF_HID + hh*1024, lane), Bh_t,
                      *(const f32x4*)(hbt + l*16 + 4*q));
            as = mfma(load_frag(bs, OFF_HID + hh*1024, lane), Bh_s,
                      *(const f32x4*)(hbs + l*16 + 4*q));
        }

        // ---- heads: 4 chunks of 16 passive feats, chunk-serial ----
        bf16x8 Bf_t = dreg_to_B(at);
        bf16x8 Bf_s = dreg_to_B(as);
        #pragma unroll
        for (int c = 0; c < 4; ++c){
            f32x4 ct = *(const f32x4*)(tb5 + l*128 + pOff + 16*c + 4*q);
            f32x4 cs = *(const f32x4*)(sb5 + l*128 + pOff + 16*c + 4*q);
            f32x4 tD = mfma(load_frag(bt, OFF_HEAD + c*1024, lane), Bf_t, ct);
            f32x4 sD = mfma(load_frag(bs, OFF_HEAD + c*1024, lane), Bf_s, cs);

            float4 xpv = xpl[c][tid];
            float xq[4] = {xpv.x, xpv.y, xpv.z, xpv.w};
            float nv[4];
            #pragma unroll
            for (int r = 0; r < 4; ++r){
                float u  = exp2f(sD[r] * 2.885390081777927f);                 // e^(2s), inf-safe
                float rr = __builtin_amdgcn_rcpf(u + 1.f);
                float se = fmaf(-2.f, rr, 1.f);                               // tanh(s)
                float e  = exp2f(fmaf(rr, 2.885390081777927f,
                                      -1.4426950408889634f));                 // exp(-tanh(s))
                nv[r] = (xq[r] - tD[r]) * e;
                sacc += se;
            }
            xpl[c][tid] = xa[c];                                  // old active -> passive
            xa[c] = (float4){nv[0], nv[1], nv[2], nv[3]};         // new active
        }
    }

    // final: xa = feats [0,64), xpl = feats [64,128)
    if (row < B){
        float* yrow = Y + (size_t)row * DD;
        #pragma unroll
        for (int j = 0; j < 4; ++j){
            const int off = 16*j + 4*q;
            *(float4*)(yrow + off)      = xa[j];
            *(float4*)(yrow + 64 + off) = xpl[j][tid];
        }
        float ls = sacc;
        ls += __shfl_xor(ls, 16, 64);
        ls += __shfl_xor(ls, 32, 64);
        if (q == 0) LD[row] = -ls;
    }
}

extern "C" void kernel_launch(void* const* d_in, const int* in_sizes, int n_in,
                              void* d_out, int out_size, void* d_ws, size_t ws_size,
                              hipStream_t stream)
{
    const float* X   = (const float*)d_in[0];
    const float* tW1 = (const float*)d_in[2];  const float* tb1 = (const float*)d_in[3];
    const float* tW2 = (const float*)d_in[4];  const float* tb2 = (const float*)d_in[5];
    const float* tW3 = (const float*)d_in[6];  const float* tb3 = (const float*)d_in[7];
    const float* tW4 = (const float*)d_in[8];  const float* tb4 = (const float*)d_in[9];
    const float* tW5 = (const float*)d_in[10]; const float* tb5 = (const float*)d_in[11];
    const float* sW1 = (const float*)d_in[12]; const float* sb1 = (const float*)d_in[13];
    const float* sW2 = (const float*)d_in[14]; const float* sb2 = (const float*)d_in[15];
    const float* sW3 = (const float*)d_in[16]; const float* sb3 = (const float*)d_in[17];
    const float* sW4 = (const float*)d_in[18]; const float* sb4 = (const float*)d_in[19];
    const float* sW5 = (const float*)d_in[20]; const float* sb5 = (const float*)d_in[21];

    const int B = in_sizes[0] / DD;
    float* Y  = (float*)d_out;
    float* LD = Y + (size_t)B * DD;

    unsigned char* pw = (unsigned char*)d_ws;   // needs 12*9216 = 110,592 B
    hipLaunchKernelGGL(pack_frags, dim3(NL * 2), dim3(256), 0, stream,
                       tW1, tW2, tW3, tW4, tW5, sW1, sW2, sW3, sW4, sW5, pw);

    const int nwaves = (B + 15) / 16;
    const int blocks = (nwaves + 3) / 4;        // 4 waves (256 thr) per block
    hipLaunchKernelGGL(realnvp_mfma16, dim3(blocks), dim3(256), 0, stream,
                       X, pw, tb1, tb2, tb3, tb4, tb5, sb1, sb2, sb3, sb4, sb5,
                       Y, LD, B);
}

// Round 8
// 72.266 us; speedup vs baseline: 6.9982x; 1.0706x over previous
//
#include <hip/hip_runtime.h>
#include <math.h>

#define NL 6
#define DD 128

typedef __bf16 bf16x8 __attribute__((ext_vector_type(8)));
typedef float  f32x4  __attribute__((ext_vector_type(4)));

// Frag file per (layer l, net p), base = (l*2+p)*NET_STRIDE (bytes):
//   [0,2048)    trunk A: 2 K-slices x (64 lanes x 16B)
//   [2048,5120) hidden A: 3 x (64 x 16B)   (slots e>=4 zero)
//   [5120,9216) head  A: 4 chunks x (64 x 16B) (slots e>=4 zero)
// Slot map (consistent in A and B, so internal order cancels):
//   slot(q,e) -> logical k = (e<4) ? 4q+e : 16+4q+(e-4)
#define NET_STRIDE 9216
#define OFF_HID    2048
#define OFF_HEAD   5120

static __device__ __forceinline__ unsigned cvt_pk_bf16(float lo, float hi){
    unsigned r;
    asm("v_cvt_pk_bf16_f32 %0, %1, %2" : "=v"(r) : "v"(lo), "v"(hi));
    return r;
}
static __device__ __forceinline__ f32x4 mfma(bf16x8 a, bf16x8 b, f32x4 c){
    return __builtin_amdgcn_mfma_f32_16x16x32_bf16(a, b, c, 0, 0, 0);
}
static __device__ __forceinline__ bf16x8 frag4(unsigned w0, unsigned w1, unsigned w2, unsigned w3){
    int4 v; v.x=(int)w0; v.y=(int)w1; v.z=(int)w2; v.w=(int)w3;
    return __builtin_bit_cast(bf16x8, v);
}
// relu(D regs) -> B-frag for K=16 layers. D feat = 4q+r matches B slot k=4q+e directly.
static __device__ __forceinline__ bf16x8 dreg_to_B(f32x4 d){
    unsigned w0 = cvt_pk_bf16(fmaxf(d[0],0.f), fmaxf(d[1],0.f));
    unsigned w1 = cvt_pk_bf16(fmaxf(d[2],0.f), fmaxf(d[3],0.f));
    return frag4(w0, w1, 0u, 0u);
}
static __device__ __forceinline__ bf16x8 load_frag(const unsigned char* nb, int off, int lane){
    return *(const bf16x8*)(nb + off + lane * 16);
}
// epilogue: y = (xp - t)*exp(-tanh(s)); swap xa/xp; accumulate tanh(s)
static __device__ __forceinline__ void epi(f32x4 tD, f32x4 sD,
                                           float4 &xa, float4 &xp, float &sacc){
    float xq[4] = {xp.x, xp.y, xp.z, xp.w};
    float nv[4];
    #pragma unroll
    for (int r = 0; r < 4; ++r){
        float u  = exp2f(sD[r] * 2.885390081777927f);                 // e^(2s), inf-safe
        float rr = __builtin_amdgcn_rcpf(u + 1.f);
        float se = fmaf(-2.f, rr, 1.f);                               // tanh(s)
        float e  = exp2f(fmaf(rr, 2.885390081777927f,
                              -1.4426950408889634f));                 // exp(-tanh(s))
        nv[r] = (xq[r] - tD[r]) * e;
        sacc += se;
    }
    xp = xa;
    xa = (float4){nv[0], nv[1], nv[2], nv[3]};
}

// ---------- pack kernel (weights only; biases consumed in natural order) ----------
static __device__ __forceinline__ unsigned short f2bf_rne(float f){
    unsigned u = __float_as_uint(f);
    u += 0x7FFFu + ((u >> 16) & 1u);
    return (unsigned short)(u >> 16);
}

__global__ void pack_frags(
    const float* __restrict__ tW1, const float* __restrict__ tW2,
    const float* __restrict__ tW3, const float* __restrict__ tW4,
    const float* __restrict__ tW5,
    const float* __restrict__ sW1, const float* __restrict__ sW2,
    const float* __restrict__ sW3, const float* __restrict__ sW4,
    const float* __restrict__ sW5,
    unsigned char* __restrict__ pw)
{
    const int bx = blockIdx.x;           // = l*2 + p
    const int l = bx >> 1, p = bx & 1;
    const int aOff = (l & 1) ? 0 : 64;
    const int pOff = 64 - aOff;
    const float* W1 = p ? sW1 : tW1;
    const float* W2 = p ? sW2 : tW2;
    const float* W3 = p ? sW3 : tW3;
    const float* W4 = p ? sW4 : tW4;
    const float* W5 = p ? sW5 : tW5;
    unsigned char* base = pw + (size_t)bx * NET_STRIDE;

    for (int t = threadIdx.x; t < 576; t += blockDim.x){
        const int lane = t & 63, m = lane & 15, q = lane >> 4;
        unsigned short v[8];
        unsigned char* dst;
        if (t < 128){                    // trunk: full K=32 slices
            int slice = t >> 6;
            #pragma unroll
            for (int e = 0; e < 8; ++e){
                int sg = (e < 4) ? (4*q + e) : (16 + 4*q + (e - 4));
                v[e] = f2bf_rne(W1[l*2048 + (aOff + 32*slice + sg)*16 + m]);
            }
            dst = base + slice*1024 + lane*16;
        } else if (t < 320){             // hidden: K=16 in slots e<4, zeros above
            int hh = (t - 128) >> 6;
            const float* W = (hh == 0) ? W2 : (hh == 1) ? W3 : W4;
            #pragma unroll
            for (int e = 0; e < 8; ++e)
                v[e] = (e < 4) ? f2bf_rne(W[l*256 + (4*q + e)*16 + m]) : (unsigned short)0;
            dst = base + OFF_HID + hh*1024 + lane*16;
        } else {                         // head chunk c: passive feats pOff+16c+m
            int c = (t - 320) >> 6;
            #pragma unroll
            for (int e = 0; e < 8; ++e)
                v[e] = (e < 4) ? f2bf_rne(W5[l*2048 + (4*q + e)*128 + pOff + 16*c + m])
                               : (unsigned short)0;
            dst = base + OFF_HEAD + c*1024 + lane*16;
        }
        int4 o;
        o.x = (int)((unsigned)v[0] | ((unsigned)v[1] << 16));
        o.y = (int)((unsigned)v[2] | ((unsigned)v[3] << 16));
        o.z = (int)((unsigned)v[4] | ((unsigned)v[5] << 16));
        o.w = (int)((unsigned)v[6] | ((unsigned)v[7] << 16));
        *(int4*)dst = o;
    }
}

// ---------- main kernel: 2 x 16-row tiles per wave; A-frags/biases loaded once, used twice ----------
__global__ __launch_bounds__(256, 4)
void realnvp_mfma16x2(const float* __restrict__ X, const unsigned char* __restrict__ PW,
    const float* __restrict__ tb1, const float* __restrict__ tb2,
    const float* __restrict__ tb3, const float* __restrict__ tb4,
    const float* __restrict__ tb5,
    const float* __restrict__ sb1, const float* __restrict__ sb2,
    const float* __restrict__ sb3, const float* __restrict__ sb4,
    const float* __restrict__ sb5,
    float* __restrict__ Y, float* __restrict__ LD, int B)
{
    __shared__ float4 xpl[8][256];       // passive halves, tile0 in [0:4), tile1 in [4:8)  (32 KB)
    const int tid  = threadIdx.x;
    const int lane = tid & 63;
    const int wid  = blockIdx.x * 4 + (tid >> 6);
    const int q = lane >> 4, n = lane & 15;
    const int r0 = wid * 32 + n;
    const int r1 = r0 + 16;
    if (wid * 32 >= B) return;
    const int r0c = (r0 < B) ? r0 : (B - 1);
    const int r1c = (r1 < B) ? r1 : (B - 1);

    const float* x0 = X + (size_t)r0c * DD;
    const float* x1 = X + (size_t)r1c * DD;
    float4 xa0[4], xa1[4];
    #pragma unroll
    for (int j = 0; j < 4; ++j){
        const int off = 16*j + 4*q;
        xa0[j]          = *(const float4*)(x0 + off);
        xpl[j][tid]     = *(const float4*)(x0 + 64 + off);
        xa1[j]          = *(const float4*)(x1 + off);
        xpl[4 + j][tid] = *(const float4*)(x1 + 64 + off);
    }
    float sacc0 = 0.f, sacc1 = 0.f;

    #pragma unroll 1
    for (int step = 0; step < NL; ++step){
        const int l = NL - 1 - step;
        const int pOff = (l & 1) ? 64 : 0;
        const unsigned char* bt = PW + (size_t)(l * 2 + 0) * NET_STRIDE;
        const unsigned char* bs = PW + (size_t)(l * 2 + 1) * NET_STRIDE;

        // ---- trunk B-frags (per tile) ----
        bf16x8 B00 = frag4(cvt_pk_bf16(xa0[0].x, xa0[0].y), cvt_pk_bf16(xa0[0].z, xa0[0].w),
                           cvt_pk_bf16(xa0[1].x, xa0[1].y), cvt_pk_bf16(xa0[1].z, xa0[1].w));
        bf16x8 B01 = frag4(cvt_pk_bf16(xa0[2].x, xa0[2].y), cvt_pk_bf16(xa0[2].z, xa0[2].w),
                           cvt_pk_bf16(xa0[3].x, xa0[3].y), cvt_pk_bf16(xa0[3].z, xa0[3].w));
        bf16x8 B10 = frag4(cvt_pk_bf16(xa1[0].x, xa1[0].y), cvt_pk_bf16(xa1[0].z, xa1[0].w),
                           cvt_pk_bf16(xa1[1].x, xa1[1].y), cvt_pk_bf16(xa1[1].z, xa1[1].w));
        bf16x8 B11 = frag4(cvt_pk_bf16(xa1[2].x, xa1[2].y), cvt_pk_bf16(xa1[2].z, xa1[2].w),
                           cvt_pk_bf16(xa1[3].x, xa1[3].y), cvt_pk_bf16(xa1[3].z, xa1[3].w));

        // ---- trunk: K=64 as 2 x K32; A-frags + bias loaded once, used for both tiles ----
        f32x4 cbt = *(const f32x4*)(tb1 + l*16 + 4*q);
        f32x4 cbs = *(const f32x4*)(sb1 + l*16 + 4*q);
        bf16x8 A0t = load_frag(bt, 0, lane), A1t = load_frag(bt, 1024, lane);
        bf16x8 A0s = load_frag(bs, 0, lane), A1s = load_frag(bs, 1024, lane);
        f32x4 at0 = mfma(A0t, B00, cbt); at0 = mfma(A1t, B01, at0);
        f32x4 at1 = mfma(A0t, B10, cbt); at1 = mfma(A1t, B11, at1);
        f32x4 as0 = mfma(A0s, B00, cbs); as0 = mfma(A1s, B01, as0);
        f32x4 as1 = mfma(A0s, B10, cbs); as1 = mfma(A1s, B11, as1);

        // ---- 3 hidden 16x16 layers ----
        #pragma unroll
        for (int hh = 0; hh < 3; ++hh){
            const float* hbt = (hh == 0) ? tb2 : (hh == 1) ? tb3 : tb4;
            const float* hbs = (hh == 0) ? sb2 : (hh == 1) ? sb3 : sb4;
            f32x4 ct = *(const f32x4*)(hbt + l*16 + 4*q);
            f32x4 cs = *(const f32x4*)(hbs + l*16 + 4*q);
            bf16x8 At = load_frag(bt, OFF_HID + hh*1024, lane);
            bf16x8 As = load_frag(bs, OFF_HID + hh*1024, lane);
            at0 = mfma(At, dreg_to_B(at0), ct);
            at1 = mfma(At, dreg_to_B(at1), ct);
            as0 = mfma(As, dreg_to_B(as0), cs);
            as1 = mfma(As, dreg_to_B(as1), cs);
        }

        // ---- heads: 4 chunks of 16 passive feats, chunk-serial ----
        bf16x8 Bf_t0 = dreg_to_B(at0), Bf_t1 = dreg_to_B(at1);
        bf16x8 Bf_s0 = dreg_to_B(as0), Bf_s1 = dreg_to_B(as1);
        #pragma unroll
        for (int c = 0; c < 4; ++c){
            f32x4 ct = *(const f32x4*)(tb5 + l*128 + pOff + 16*c + 4*q);
            f32x4 cs = *(const f32x4*)(sb5 + l*128 + pOff + 16*c + 4*q);
            bf16x8 Aht = load_frag(bt, OFF_HEAD + c*1024, lane);
            bf16x8 Ahs = load_frag(bs, OFF_HEAD + c*1024, lane);
            f32x4 tD0 = mfma(Aht, Bf_t0, ct);
            f32x4 sD0 = mfma(Ahs, Bf_s0, cs);
            f32x4 tD1 = mfma(Aht, Bf_t1, ct);
            f32x4 sD1 = mfma(Ahs, Bf_s1, cs);

            float4 xp0 = xpl[c][tid];
            epi(tD0, sD0, xa0[c], xp0, sacc0);
            xpl[c][tid] = xp0;

            float4 xp1 = xpl[4 + c][tid];
            epi(tD1, sD1, xa1[c], xp1, sacc1);
            xpl[4 + c][tid] = xp1;
        }
    }

    // final: xa = feats [0,64), xpl = feats [64,128)
    if (r0 < B){
        float* y0 = Y + (size_t)r0 * DD;
        #pragma unroll
        for (int j = 0; j < 4; ++j){
            const int off = 16*j + 4*q;
            *(float4*)(y0 + off)      = xa0[j];
            *(float4*)(y0 + 64 + off) = xpl[j][tid];
        }
        float ls = sacc0;
        ls += __shfl_xor(ls, 16, 64);
        ls += __shfl_xor(ls, 32, 64);
        if (q == 0) LD[r0] = -ls;
    }
    if (r1 < B){
        float* y1 = Y + (size_t)r1 * DD;
        #pragma unroll
        for (int j = 0; j < 4; ++j){
            const int off = 16*j + 4*q;
            *(float4*)(y1 + off)      = xa1[j];
            *(float4*)(y1 + 64 + off) = xpl[4 + j][tid];
        }
        float ls = sacc1;
        ls += __shfl_xor(ls, 16, 64);
        ls += __shfl_xor(ls, 32, 64);
        if (q == 0) LD[r1] = -ls;
    }
}

extern "C" void kernel_launch(void* const* d_in, const int* in_sizes, int n_in,
                              void* d_out, int out_size, void* d_ws, size_t ws_size,
                              hipStream_t stream)
{
    const float* X   = (const float*)d_in[0];
    const float* tW1 = (const float*)d_in[2];  const float* tb1 = (const float*)d_in[3];
    const float* tW2 = (const float*)d_in[4];  const float* tb2 = (const float*)d_in[5];
    const float* tW3 = (const float*)d_in[6];  const float* tb3 = (const float*)d_in[7];
    const float* tW4 = (const float*)d_in[8];  const float* tb4 = (const float*)d_in[9];
    const float* tW5 = (const float*)d_in[10]; const float* tb5 = (const float*)d_in[11];
    const float* sW1 = (const float*)d_in[12]; const float* sb1 = (const float*)d_in[13];
    const float* sW2 = (const float*)d_in[14]; const float* sb2 = (const float*)d_in[15];
    const float* sW3 = (const float*)d_in[16]; const float* sb3 = (const float*)d_in[17];
    const float* sW4 = (const float*)d_in[18]; const float* sb4 = (const float*)d_in[19];
    const float* sW5 = (const float*)d_in[20]; const float* sb5 = (const float*)d_in[21];

    const int B = in_sizes[0] / DD;
    float* Y  = (float*)d_out;
    float* LD = Y + (size_t)B * DD;

    unsigned char* pw = (unsigned char*)d_ws;   // needs 12*9216 = 110,592 B
    hipLaunchKernelGGL(pack_frags, dim3(NL * 2), dim3(256), 0, stream,
                       tW1, tW2, tW3, tW4, tW5, sW1, sW2, sW3, sW4, sW5, pw);

    const int nwaves = (B + 31) / 32;
    const int blocks = (nwaves + 3) / 4;        // 4 waves (256 thr) per block
    hipLaunchKernelGGL(realnvp_mfma16x2, dim3(blocks), dim3(256), 0, stream,
                       X, pw, tb1, tb2, tb3, tb4, tb5, sb1, sb2, sb3, sb4, sb5,
                       Y, LD, B);
}

// Round 13
// 69.231 us; speedup vs baseline: 7.3051x; 1.0438x over previous
//
#include <hip/hip_runtime.h>
#include <math.h>

#define NL 6
#define DD 128

typedef __bf16 bf16x8 __attribute__((ext_vector_type(8)));
typedef float  f32x4  __attribute__((ext_vector_type(4)));

// Frag file per (layer l, net p), base = (l*2+p)*NET_STRIDE (bytes):
//   [0,2048)    trunk A: 2 K-slices x (64 lanes x 16B)
//   [2048,5120) hidden A: 3 x (64 x 16B)   (slots e>=4 zero)
//   [5120,9216) head  A: 4 chunks x (64 x 16B) (slots e>=4 zero)
// Slot map (consistent in A and B, so internal order cancels):
//   slot(q,e) -> logical k = (e<4) ? 4q+e : 16+4q+(e-4)
#define NET_STRIDE 9216
#define OFF_HID    2048
#define OFF_HEAD   5120

static __device__ __forceinline__ unsigned cvt_pk_bf16(float lo, float hi){
    unsigned r;
    asm("v_cvt_pk_bf16_f32 %0, %1, %2" : "=v"(r) : "v"(lo), "v"(hi));
    return r;
}
static __device__ __forceinline__ f32x4 mfma(bf16x8 a, bf16x8 b, f32x4 c){
    return __builtin_amdgcn_mfma_f32_16x16x32_bf16(a, b, c, 0, 0, 0);
}
static __device__ __forceinline__ bf16x8 frag4(unsigned w0, unsigned w1, unsigned w2, unsigned w3){
    int4 v; v.x=(int)w0; v.y=(int)w1; v.z=(int)w2; v.w=(int)w3;
    return __builtin_bit_cast(bf16x8, v);
}
// relu(D regs) -> B-frag for K=16 layers. D feat = 4q+r matches B slot k=4q+e directly.
static __device__ __forceinline__ bf16x8 dreg_to_B(f32x4 d){
    unsigned w0 = cvt_pk_bf16(fmaxf(d[0],0.f), fmaxf(d[1],0.f));
    unsigned w1 = cvt_pk_bf16(fmaxf(d[2],0.f), fmaxf(d[3],0.f));
    return frag4(w0, w1, 0u, 0u);
}
static __device__ __forceinline__ bf16x8 load_frag(const unsigned char* nb, int off, int lane){
    return *(const bf16x8*)(nb + off + lane * 16);
}
// ONLY change vs round-8: y = (xp - t)*e^z with z = 2*rcp(e^{2s}+1)-1 = -tanh(s),
// e^z via deg-5 poly on [-1,1] (err ~5e-5). 2 transcendentals instead of 3.
// zacc accumulates z, so LD = +sum(z) = -sum(tanh s).
static __device__ __forceinline__ void epi(f32x4 tD, f32x4 sD,
                                           float4 &xa, float4 &xp, float &zacc){
    float xq[4] = {xp.x, xp.y, xp.z, xp.w};
    float nv[4];
    #pragma unroll
    for (int r = 0; r < 4; ++r){
        float u  = exp2f(sD[r] * 2.885390081777927f);      // e^{2s} (sat inf/0, safe)
        float rr = __builtin_amdgcn_rcpf(u + 1.f);
        float z  = fmaf(2.f, rr, -1.f);                    // -tanh(s) in [-1,1]
        float p  = fmaf(0.0086868208f, z, 0.0437939232f);  // e^z
        p = fmaf(p, z, 0.1664888732f);
        p = fmaf(p, z, 0.4991967560f);
        p = fmaf(p, z, 1.0000222901f);
        p = fmaf(p, z, 1.0000447786f);
        zacc += z;
        nv[r] = (xq[r] - tD[r]) * p;
    }
    xp = xa;
    xa = (float4){nv[0], nv[1], nv[2], nv[3]};
}

// ---------- pack kernel (byte-identical to round 8) ----------
static __device__ __forceinline__ unsigned short f2bf_rne(float f){
    unsigned u = __float_as_uint(f);
    u += 0x7FFFu + ((u >> 16) & 1u);
    return (unsigned short)(u >> 16);
}

__global__ void pack_frags(
    const float* __restrict__ tW1, const float* __restrict__ tW2,
    const float* __restrict__ tW3, const float* __restrict__ tW4,
    const float* __restrict__ tW5,
    const float* __restrict__ sW1, const float* __restrict__ sW2,
    const float* __restrict__ sW3, const float* __restrict__ sW4,
    const float* __restrict__ sW5,
    unsigned char* __restrict__ pw)
{
    const int bx = blockIdx.x;           // = l*2 + p
    const int l = bx >> 1, p = bx & 1;
    const int aOff = (l & 1) ? 0 : 64;
    const int pOff = 64 - aOff;
    const float* W1 = p ? sW1 : tW1;
    const float* W2 = p ? sW2 : tW2;
    const float* W3 = p ? sW3 : tW3;
    const float* W4 = p ? sW4 : tW4;
    const float* W5 = p ? sW5 : tW5;
    unsigned char* base = pw + (size_t)bx * NET_STRIDE;

    for (int t = threadIdx.x; t < 576; t += blockDim.x){
        const int lane = t & 63, m = lane & 15, q = lane >> 4;
        unsigned short v[8];
        unsigned char* dst;
        if (t < 128){                    // trunk: full K=32 slices
            int slice = t >> 6;
            #pragma unroll
            for (int e = 0; e < 8; ++e){
                int sg = (e < 4) ? (4*q + e) : (16 + 4*q + (e - 4));
                v[e] = f2bf_rne(W1[l*2048 + (aOff + 32*slice + sg)*16 + m]);
            }
            dst = base + slice*1024 + lane*16;
        } else if (t < 320){             // hidden: K=16 in slots e<4, zeros above
            int hh = (t - 128) >> 6;
            const float* W = (hh == 0) ? W2 : (hh == 1) ? W3 : W4;
            #pragma unroll
            for (int e = 0; e < 8; ++e)
                v[e] = (e < 4) ? f2bf_rne(W[l*256 + (4*q + e)*16 + m]) : (unsigned short)0;
            dst = base + OFF_HID + hh*1024 + lane*16;
        } else {                         // head chunk c: passive feats pOff+16c+m
            int c = (t - 320) >> 6;
            #pragma unroll
            for (int e = 0; e < 8; ++e)
                v[e] = (e < 4) ? f2bf_rne(W5[l*2048 + (4*q + e)*128 + pOff + 16*c + m])
                               : (unsigned short)0;
            dst = base + OFF_HEAD + c*1024 + lane*16;
        }
        int4 o;
        o.x = (int)((unsigned)v[0] | ((unsigned)v[1] << 16));
        o.y = (int)((unsigned)v[2] | ((unsigned)v[3] << 16));
        o.z = (int)((unsigned)v[4] | ((unsigned)v[5] << 16));
        o.w = (int)((unsigned)v[6] | ((unsigned)v[7] << 16));
        *(int4*)dst = o;
    }
}

// ---------- main kernel: identical to round 8 except epi / LD sign ----------
__global__ __launch_bounds__(256, 4)
void realnvp_mfma16x2(const float* __restrict__ X, const unsigned char* __restrict__ PW,
    const float* __restrict__ tb1, const float* __restrict__ tb2,
    const float* __restrict__ tb3, const float* __restrict__ tb4,
    const float* __restrict__ tb5,
    const float* __restrict__ sb1, const float* __restrict__ sb2,
    const float* __restrict__ sb3, const float* __restrict__ sb4,
    const float* __restrict__ sb5,
    float* __restrict__ Y, float* __restrict__ LD, int B)
{
    __shared__ float4 xpl[8][256];       // passive halves, tile0 in [0:4), tile1 in [4:8)
    const int tid  = threadIdx.x;
    const int lane = tid & 63;
    const int wid  = blockIdx.x * 4 + (tid >> 6);
    const int q = lane >> 4, n = lane & 15;
    const int r0 = wid * 32 + n;
    const int r1 = r0 + 16;
    if (wid * 32 >= B) return;
    const int r0c = (r0 < B) ? r0 : (B - 1);
    const int r1c = (r1 < B) ? r1 : (B - 1);

    const float* x0 = X + (size_t)r0c * DD;
    const float* x1 = X + (size_t)r1c * DD;
    float4 xa0[4], xa1[4];
    #pragma unroll
    for (int j = 0; j < 4; ++j){
        const int off = 16*j + 4*q;
        xa0[j]          = *(const float4*)(x0 + off);
        xpl[j][tid]     = *(const float4*)(x0 + 64 + off);
        xa1[j]          = *(const float4*)(x1 + off);
        xpl[4 + j][tid] = *(const float4*)(x1 + 64 + off);
    }
    float zacc0 = 0.f, zacc1 = 0.f;

    #pragma unroll 1
    for (int step = 0; step < NL; ++step){
        const int l = NL - 1 - step;
        const int pOff = (l & 1) ? 64 : 0;
        const unsigned char* bt = PW + (size_t)(l * 2 + 0) * NET_STRIDE;
        const unsigned char* bs = PW + (size_t)(l * 2 + 1) * NET_STRIDE;

        // ---- trunk B-frags (per tile) ----
        bf16x8 B00 = frag4(cvt_pk_bf16(xa0[0].x, xa0[0].y), cvt_pk_bf16(xa0[0].z, xa0[0].w),
                           cvt_pk_bf16(xa0[1].x, xa0[1].y), cvt_pk_bf16(xa0[1].z, xa0[1].w));
        bf16x8 B01 = frag4(cvt_pk_bf16(xa0[2].x, xa0[2].y), cvt_pk_bf16(xa0[2].z, xa0[2].w),
                           cvt_pk_bf16(xa0[3].x, xa0[3].y), cvt_pk_bf16(xa0[3].z, xa0[3].w));
        bf16x8 B10 = frag4(cvt_pk_bf16(xa1[0].x, xa1[0].y), cvt_pk_bf16(xa1[0].z, xa1[0].w),
                           cvt_pk_bf16(xa1[1].x, xa1[1].y), cvt_pk_bf16(xa1[1].z, xa1[1].w));
        bf16x8 B11 = frag4(cvt_pk_bf16(xa1[2].x, xa1[2].y), cvt_pk_bf16(xa1[2].z, xa1[2].w),
                           cvt_pk_bf16(xa1[3].x, xa1[3].y), cvt_pk_bf16(xa1[3].z, xa1[3].w));

        // ---- trunk: K=64 as 2 x K32; A-frags + bias loaded once, used for both tiles ----
        f32x4 cbt = *(const f32x4*)(tb1 + l*16 + 4*q);
        f32x4 cbs = *(const f32x4*)(sb1 + l*16 + 4*q);
        bf16x8 A0t = load_frag(bt, 0, lane), A1t = load_frag(bt, 1024, lane);
        bf16x8 A0s = load_frag(bs, 0, lane), A1s = load_frag(bs, 1024, lane);
        f32x4 at0 = mfma(A0t, B00, cbt); at0 = mfma(A1t, B01, at0);
        f32x4 at1 = mfma(A0t, B10, cbt); at1 = mfma(A1t, B11, at1);
        f32x4 as0 = mfma(A0s, B00, cbs); as0 = mfma(A1s, B01, as0);
        f32x4 as1 = mfma(A0s, B10, cbs); as1 = mfma(A1s, B11, as1);

        // ---- 3 hidden 16x16 layers ----
        #pragma unroll
        for (int hh = 0; hh < 3; ++hh){
            const float* hbt = (hh == 0) ? tb2 : (hh == 1) ? tb3 : tb4;
            const float* hbs = (hh == 0) ? sb2 : (hh == 1) ? sb3 : sb4;
            f32x4 ct = *(const f32x4*)(hbt + l*16 + 4*q);
            f32x4 cs = *(const f32x4*)(hbs + l*16 + 4*q);
            bf16x8 At = load_frag(bt, OFF_HID + hh*1024, lane);
            bf16x8 As = load_frag(bs, OFF_HID + hh*1024, lane);
            at0 = mfma(At, dreg_to_B(at0), ct);
            at1 = mfma(At, dreg_to_B(at1), ct);
            as0 = mfma(As, dreg_to_B(as0), cs);
            as1 = mfma(As, dreg_to_B(as1), cs);
        }

        // ---- heads: 4 chunks of 16 passive feats, chunk-serial ----
        bf16x8 Bf_t0 = dreg_to_B(at0), Bf_t1 = dreg_to_B(at1);
        bf16x8 Bf_s0 = dreg_to_B(as0), Bf_s1 = dreg_to_B(as1);
        #pragma unroll
        for (int c = 0; c < 4; ++c){
            f32x4 ct = *(const f32x4*)(tb5 + l*128 + pOff + 16*c + 4*q);
            f32x4 cs = *(const f32x4*)(sb5 + l*128 + pOff + 16*c + 4*q);
            bf16x8 Aht = load_frag(bt, OFF_HEAD + c*1024, lane);
            bf16x8 Ahs = load_frag(bs, OFF_HEAD + c*1024, lane);
            f32x4 tD0 = mfma(Aht, Bf_t0, ct);
            f32x4 sD0 = mfma(Ahs, Bf_s0, cs);
            f32x4 tD1 = mfma(Aht, Bf_t1, ct);
            f32x4 sD1 = mfma(Ahs, Bf_s1, cs);

            float4 xp0 = xpl[c][tid];
            epi(tD0, sD0, xa0[c], xp0, zacc0);
            xpl[c][tid] = xp0;

            float4 xp1 = xpl[4 + c][tid];
            epi(tD1, sD1, xa1[c], xp1, zacc1);
            xpl[4 + c][tid] = xp1;
        }
    }

    // final: xa = feats [0,64), xpl = feats [64,128);  LD = +sum(z) = -sum(tanh s)
    if (r0 < B){
        float* y0 = Y + (size_t)r0 * DD;
        #pragma unroll
        for (int j = 0; j < 4; ++j){
            const int off = 16*j + 4*q;
            *(float4*)(y0 + off)      = xa0[j];
            *(float4*)(y0 + 64 + off) = xpl[j][tid];
        }
        float ls = zacc0;
        ls += __shfl_xor(ls, 16, 64);
        ls += __shfl_xor(ls, 32, 64);
        if (q == 0) LD[r0] = ls;
    }
    if (r1 < B){
        float* y1 = Y + (size_t)r1 * DD;
        #pragma unroll
        for (int j = 0; j < 4; ++j){
            const int off = 16*j + 4*q;
            *(float4*)(y1 + off)      = xa1[j];
            *(float4*)(y1 + 64 + off) = xpl[4 + j][tid];
        }
        float ls = zacc1;
        ls += __shfl_xor(ls, 16, 64);
        ls += __shfl_xor(ls, 32, 64);
        if (q == 0) LD[r1] = ls;
    }
}

extern "C" void kernel_launch(void* const* d_in, const int* in_sizes, int n_in,
                              void* d_out, int out_size, void* d_ws, size_t ws_size,
                              hipStream_t stream)
{
    const float* X   = (const float*)d_in[0];
    const float* tW1 = (const float*)d_in[2];  const float* tb1 = (const float*)d_in[3];
    const float* tW2 = (const float*)d_in[4];  const float* tb2 = (const float*)d_in[5];
    const float* tW3 = (const float*)d_in[6];  const float* tb3 = (const float*)d_in[7];
    const float* tW4 = (const float*)d_in[8];  const float* tb4 = (const float*)d_in[9];
    const float* tW5 = (const float*)d_in[10]; const float* tb5 = (const float*)d_in[11];
    const float* sW1 = (const float*)d_in[12]; const float* sb1 = (const float*)d_in[13];
    const float* sW2 = (const float*)d_in[14]; const float* sb2 = (const float*)d_in[15];
    const float* sW3 = (const float*)d_in[16]; const float* sb3 = (const float*)d_in[17];
    const float* sW4 = (const float*)d_in[18]; const float* sb4 = (const float*)d_in[19];
    const float* sW5 = (const float*)d_in[20]; const float* sb5 = (const float*)d_in[21];

    const int B = in_sizes[0] / DD;
    float* Y  = (float*)d_out;
    float* LD = Y + (size_t)B * DD;

    unsigned char* pw = (unsigned char*)d_ws;   // needs 12*9216 = 110,592 B
    hipLaunchKernelGGL(pack_frags, dim3(NL * 2), dim3(256), 0, stream,
                       tW1, tW2, tW3, tW4, tW5, sW1, sW2, sW3, sW4, sW5, pw);

    const int nwaves = (B + 31) / 32;
    const int blocks = (nwaves + 3) / 4;        // 4 waves (256 thr) per block
    hipLaunchKernelGGL(realnvp_mfma16x2, dim3(blocks), dim3(256), 0, stream,
                       X, pw, tb1, tb2, tb3, tb4, tb5, sb1, sb2, sb3, sb4, sb5,
                       Y, LD, B);
}